// Round 16
// baseline (584.360 us; speedup 1.0000x reference)
//
#include <hip/hip_runtime.h>
#include <hip/hip_bf16.h>

typedef __hip_bfloat16 bf16;
typedef short s8v __attribute__((ext_vector_type(8)));   // 8 bf16 (4 VGPRs)
typedef float f32x4 __attribute__((ext_vector_type(4)));

__device__ __forceinline__ float b2f(bf16 v) { return __bfloat162float(v); }
__device__ __forceinline__ bf16 f2b(float v) { return __float2bfloat16(v); }

union H8 { bf16 h[8]; s8v v; uint2 u2[2]; };
union H4 { bf16 h[4]; unsigned int u[2]; };
union U4V { unsigned int u[4]; s8v v; };

// tanh-approx gelu in sigmoid form: 0.5x(1+tanh(y)) == x*sigmoid(2y)
__device__ __forceinline__ float gelu_f(float x) {
    float x2 = x * x;
    float t = fmaf(x2, 0.044715f, 1.0f);
    float u = x * 1.5957691216057308f * t;
    float e = __expf(-u);
    return x / (1.0f + e);
}

// async stage: copy nseg*1024B of fragment-linear image into LDS (linear dest)
__device__ __forceinline__ void stage_frag(const bf16* __restrict__ img, bf16* lds,
                                           int nseg, int wv, int lane) {
    for (int seg = wv; seg < nseg; seg += 4) {
        __builtin_amdgcn_global_load_lds(
            (const __attribute__((address_space(1))) void*)(img + seg * 512 + (lane << 3)),
            (__attribute__((address_space(3))) void*)(lds + seg * 512),
            16, 0, 0);
    }
}

// ---------------------------------------------------------------------------
// k_prep: build fragment-linear bf16 weight images in ws (unchanged).
// frag(lane,e) = W[k + e][n], k = tileK + (lane>>4)*8, n = tileN + (lane&15)
// ---------------------------------------------------------------------------
__global__ __launch_bounds__(256) void k_prep(
    const float* __restrict__ Wkv, const float* __restrict__ Wproj,
    const float* __restrict__ W1,  const float* __restrict__ W2,
    bf16* __restrict__ ws)
{
    int t = blockIdx.x * 256 + threadIdx.x;
    if (t >= 50688) return;
    int k, n, ld;
    const float* W;
    bf16* dst;
    if (t < 9216) {                 // Wkv
        int c = t / 1152, r = t % 1152;
        int tile = r >> 6, lane = r & 63;
        int ks = tile / 3, nt = tile % 3;
        n = c * 48 + nt * 16 + (lane & 15);
        k = ks * 32 + (lane >> 4) * 8;
        W = Wkv; ld = 384; dst = ws + t * 8;
    } else if (t < 13824) {         // Wproj
        int t2 = t - 9216;
        int c = t2 / 1152, r = t2 % 1152;
        int tile = r >> 6, lane = r & 63;
        int ks = tile / 3, nt = tile % 3;
        n = c * 48 + nt * 16 + (lane & 15);
        k = ks * 32 + (lane >> 4) * 8;
        W = Wproj; ld = 192; dst = ws + 73728 + t2 * 8;
    } else {                        // W1 / W2
        int t3 = t - 13824;
        int c = t3 / 1536, r = t3 % 1536;
        int half = r / 768, rr = r % 768;
        int tile = rr >> 6, lane = rr & 63;
        int lr = lane & 15, g = lane >> 4;
        if (half == 0) {            // W1[k][n0+n]
            int ks = tile >> 1, nt2 = tile & 1;
            n = c * 32 + nt2 * 16 + lr; k = ks * 32 + g * 8; W = W1; ld = 768;
        } else {                    // W2[n0+k][n]
            n = tile * 16 + lr; k = c * 32 + g * 8; W = W2; ld = 192;
        }
        dst = ws + 110592 + t3 * 8;
    }
    #pragma unroll
    for (int e = 0; e < 8; ++e) dst[e] = f2b(W[(k + e) * ld + n]);
}

// ---------------------------------------------------------------------------
// Kernel 1 (unchanged since R9): LN1 -> kv -> attention -> proj -> +skip
// grid = 4096 windows, block = 256 (4 waves).  Writes x (f32) to xout (d_out).
// ---------------------------------------------------------------------------
__global__ __launch_bounds__(256, 2) void k_attn(
    const float* __restrict__ skip, const float* __restrict__ xup,
    const float* __restrict__ g1,   const float* __restrict__ be1,
    const bf16*  __restrict__ imgKv,const float* __restrict__ bkv,
    const bf16*  __restrict__ imgPr,const float* __restrict__ bproj,
    const float* __restrict__ btab, const int*  __restrict__ relidx,
    float* __restrict__ xout)
{
    __shared__ __align__(16) bf16 sK[64 * 200];      // 25600 B
    __shared__ __align__(16) char poolRaw[36864];    // {sVt[192][72] + sP[64][72]} then sO[64][200]
    __shared__ __align__(16) float sBt[2058];        // staged bias table (8232 B)

    bf16* sVt = (bf16*)poolRaw;                // [192][72]  V^T: d x token
    bf16* sP  = (bf16*)(poolRaw + 27648);      // [64][72]   P per head (wave-private rows)
    bf16* sO  = (bf16*)poolRaw;                // [64][200]  after attention

    const int tid = threadIdx.x;
    const int lane = tid & 63;
    const int wv = tid >> 6;
    const int g = lane >> 4;        // k-group
    const int lr = lane & 15;       // A-row / B-col within 16-tile
    const int w = blockIdx.x;
    const int b = w >> 11;
    const int widx = w & 2047;
    const int d0 = widx >> 8, h0 = (widx >> 4) & 15, w0 = widx & 15;

    #define GROW(t) (b * 131072 + (d0 * 4 + ((t) >> 4)) * 4096 + \
                     (h0 * 4 + (((t) >> 2) & 3)) * 64 + (w0 * 4 + ((t) & 3)))

    // ================= Phase A: load + LN1 in registers =================
    const int myrow = wv * 16 + lr;
    const int growA = GROW(myrow) * 192;
    float4 u4[12], s4[12];
    #pragma unroll
    for (int ks = 0; ks < 6; ++ks) {
        int k0 = 32 * ks + 8 * g;
        u4[2 * ks]     = *(const float4*)(xup  + growA + k0);
        u4[2 * ks + 1] = *(const float4*)(xup  + growA + k0 + 4);
        s4[2 * ks]     = *(const float4*)(skip + growA + k0);
        s4[2 * ks + 1] = *(const float4*)(skip + growA + k0 + 4);
    }
    float su = 0, squ = 0, ss = 0, sqs = 0;
    #pragma unroll
    for (int i = 0; i < 12; ++i) {
        const float* up = &u4[i].x;
        const float* sp = &s4[i].x;
        #pragma unroll
        for (int e = 0; e < 4; ++e) {
            su += up[e]; squ += up[e] * up[e];
            ss += sp[e]; sqs += sp[e] * sp[e];
        }
    }
    su += __shfl_xor(su, 16);  su += __shfl_xor(su, 32);
    squ += __shfl_xor(squ, 16); squ += __shfl_xor(squ, 32);
    ss += __shfl_xor(ss, 16);  ss += __shfl_xor(ss, 32);
    sqs += __shfl_xor(sqs, 16); sqs += __shfl_xor(sqs, 32);
    const float inv192 = 1.f / 192.f;
    float muU = su * inv192, vU = squ * inv192 - muU * muU;
    float muS = ss * inv192, vS = sqs * inv192 - muS * muS;
    float rU = rsqrtf(vU + 1e-5f), rS = rsqrtf(vS + 1e-5f);
    const float scale = 0.17677669529663687f;   // 32^-0.5 (folded into Q)

    s8v qreg[6], sreg[6];
    #pragma unroll
    for (int ks = 0; ks < 6; ++ks) {
        H8 qa, sa;
        #pragma unroll
        for (int half = 0; half < 2; ++half) {
            const float* up = &u4[2 * ks + half].x;
            const float* sp = &s4[2 * ks + half].x;
            #pragma unroll
            for (int e = 0; e < 4; ++e) {
                int k = 32 * ks + 8 * g + 4 * half + e;
                float gg = g1[k], bb = be1[k];
                qa.h[4 * half + e] = f2b(((up[e] - muU) * rU * gg + bb) * scale);
                sa.h[4 * half + e] = f2b((sp[e] - muS) * rS * gg + bb);
            }
        }
        qreg[ks] = qa.v; sreg[ks] = sa.v;
    }

    // stage bias table into LDS (read after the post-B barrier)
    for (int i = tid; i < 2058; i += 256) sBt[i] = btab[i];

    // ================= Phase B: kv GEMM, B-frags from global (no barriers) ========
    for (int nc = 0; nc < 8; ++nc) {
        const bf16* img = imgKv + nc * 9216;
        f32x4 acc[3];
        #pragma unroll
        for (int nt = 0; nt < 3; ++nt) acc[nt] = (f32x4){0.f, 0.f, 0.f, 0.f};
        #pragma unroll
        for (int ks = 0; ks < 6; ++ks) {
            #pragma unroll
            for (int nt = 0; nt < 3; ++nt) {
                s8v bfr = *(const s8v*)(img + ((ks * 3 + nt) * 64 + lane) * 8);
                acc[nt] = __builtin_amdgcn_mfma_f32_16x16x32_bf16(sreg[ks], bfr, acc[nt], 0, 0, 0);
            }
        }
        if (nc < 4) {             // K columns -> sK[token][c]
            #pragma unroll
            for (int nt = 0; nt < 3; ++nt) {
                int c = nc * 48 + nt * 16 + lr;
                float bias = bkv[c];
                #pragma unroll
                for (int e = 0; e < 4; ++e)
                    sK[(wv * 16 + 4 * g + e) * 200 + c] = f2b(acc[nt][e] + bias);
            }
        } else {                  // V columns -> transposed sVt[d][token] (packed)
            #pragma unroll
            for (int nt = 0; nt < 3; ++nt) {
                int c = nc * 48 + nt * 16 + lr;
                float bias = bkv[c];
                int d = c - 192;
                H8 t4;
                #pragma unroll
                for (int e = 0; e < 4; ++e) t4.h[e] = f2b(acc[nt][e] + bias);
                *(uint2*)(sVt + d * 72 + wv * 16 + 4 * g) = t4.u2[0];
            }
        }
    }

    int bidx[4][4];
    #pragma unroll
    for (int nt = 0; nt < 4; ++nt)
        #pragma unroll
        for (int e = 0; e < 4; ++e)
            bidx[nt][e] = relidx[(wv * 16 + lr) * 64 + nt * 16 + 4 * g + e] * 6;

    __syncthreads();   // BARRIER 1: sK/sVt/sBt visible to all waves

    // ================= Phase C: attention per head (no barriers) =================
    f32x4 accOT[6][2];
    #pragma unroll
    for (int h = 0; h < 6; ++h)
        #pragma unroll
        for (int nt = 0; nt < 2; ++nt) accOT[h][nt] = (f32x4){0.f, 0.f, 0.f, 0.f};

    #pragma unroll
    for (int h = 0; h < 6; ++h) {
        f32x4 s[4];
        #pragma unroll
        for (int nt = 0; nt < 4; ++nt) {
            s8v kf = *(const s8v*)(sK + (nt * 16 + lr) * 200 + h * 32 + 8 * g);
            s[nt] = __builtin_amdgcn_mfma_f32_16x16x32_bf16(kf, qreg[h],
                        (f32x4){0.f, 0.f, 0.f, 0.f}, 0, 0, 0);
        }
        #pragma unroll
        for (int nt = 0; nt < 4; ++nt)
            #pragma unroll
            for (int e = 0; e < 4; ++e)
                s[nt][e] += sBt[bidx[nt][e] + h];
        float mx = -1e30f;
        #pragma unroll
        for (int nt = 0; nt < 4; ++nt)
            #pragma unroll
            for (int e = 0; e < 4; ++e) mx = fmaxf(mx, s[nt][e]);
        mx = fmaxf(mx, __shfl_xor(mx, 16));
        mx = fmaxf(mx, __shfl_xor(mx, 32));
        float sm = 0;
        #pragma unroll
        for (int nt = 0; nt < 4; ++nt)
            #pragma unroll
            for (int e = 0; e < 4; ++e) { s[nt][e] = __expf(s[nt][e] - mx); sm += s[nt][e]; }
        sm += __shfl_xor(sm, 16);
        sm += __shfl_xor(sm, 32);
        float iv = 1.f / sm;
        #pragma unroll
        for (int nt = 0; nt < 4; ++nt) {
            H8 pk;
            #pragma unroll
            for (int e = 0; e < 4; ++e) pk.h[e] = f2b(s[nt][e] * iv);
            *(uint2*)(sP + (wv * 16 + lr) * 72 + nt * 16 + 4 * g) = pk.u2[0];
        }
        s8v aP0 = *(const s8v*)(sP + (wv * 16 + lr) * 72 + 8 * g);
        s8v aP1 = *(const s8v*)(sP + (wv * 16 + lr) * 72 + 32 + 8 * g);
        #pragma unroll
        for (int nt = 0; nt < 2; ++nt) {
            const bf16* vb = sVt + (h * 32 + nt * 16 + lr) * 72;
            s8v v0 = *(const s8v*)(vb + 8 * g);
            s8v v1 = *(const s8v*)(vb + 32 + 8 * g);
            accOT[h][nt] = __builtin_amdgcn_mfma_f32_16x16x32_bf16(v0, aP0, accOT[h][nt], 0, 0, 0);
            accOT[h][nt] = __builtin_amdgcn_mfma_f32_16x16x32_bf16(v1, aP1, accOT[h][nt], 0, 0, 0);
        }
    }

    __syncthreads();   // BARRIER 2: all PV reads of sVt/sP done -> sO may overwrite

    #pragma unroll
    for (int h = 0; h < 6; ++h)
        #pragma unroll
        for (int nt = 0; nt < 2; ++nt) {
            H8 pk;
            #pragma unroll
            for (int e = 0; e < 4; ++e) pk.h[e] = f2b(accOT[h][nt][e]);
            *(uint2*)(sO + (wv * 16 + lr) * 200 + h * 32 + nt * 16 + 4 * g) = pk.u2[0];
        }
    s8v aO[6];
    #pragma unroll
    for (int ks = 0; ks < 6; ++ks)
        aO[ks] = *(const s8v*)(sO + (wv * 16 + lr) * 200 + 32 * ks + 8 * g);

    // ================= Phase D: proj, B-frags from global (no barriers) ==========
    int gq[4];
    #pragma unroll
    for (int e = 0; e < 4; ++e) gq[e] = GROW(wv * 16 + 4 * g + e) * 192;

    for (int nc = 0; nc < 4; ++nc) {
        const bf16* img = imgPr + nc * 9216;
        f32x4 acc[3];
        #pragma unroll
        for (int nt = 0; nt < 3; ++nt) acc[nt] = (f32x4){0.f, 0.f, 0.f, 0.f};
        #pragma unroll
        for (int ks = 0; ks < 6; ++ks) {
            #pragma unroll
            for (int nt = 0; nt < 3; ++nt) {
                s8v bfr = *(const s8v*)(img + ((ks * 3 + nt) * 64 + lane) * 8);
                acc[nt] = __builtin_amdgcn_mfma_f32_16x16x32_bf16(aO[ks], bfr, acc[nt], 0, 0, 0);
            }
        }
        #pragma unroll
        for (int nt = 0; nt < 3; ++nt) {
            int c = nc * 48 + nt * 16 + lr;
            float bp = bproj[c];
            #pragma unroll
            for (int e = 0; e < 4; ++e) {
                int go = gq[e] + c;
                xout[go] = acc[nt][e] + bp + skip[go];
            }
        }
    }
    #undef GROW
}

// ---------------------------------------------------------------------------
// Kernel 2 (MFMA, 64 rows/block to HALVE register footprint incl. AGPRs):
// out = x + (gelu(LN2(x) @ W1 + b1) @ W2 + b2), in place on d_out.
// grid = 4096 (64 rows/block), block = 256 (4 waves, 1 M-tile each).
// 2-buffer counted-vmcnt staging; shuffle relayout; LDS = 49152 B.
// accC[12]=48 regs (was 96) -> total VGPR+AGPR ~120 -> 3 waves/SIMD.
// ---------------------------------------------------------------------------
__global__ __launch_bounds__(256, 3) void k_mlp(
    float* __restrict__ xio,
    const float* __restrict__ g2, const float* __restrict__ be2,
    const bf16*  __restrict__ imgMlp,
    const float* __restrict__ b1, const float* __restrict__ b2)
{
    __shared__ __align__(1024) bf16 sW[2][12288];   // 2 x 24576 B chunk images

    const int tid = threadIdx.x;
    const int lane = tid & 63;
    const int wv = tid >> 6;
    const int g = lane >> 4;
    const int lr = lane & 15;
    const int rowbase = blockIdx.x * 64;

    // prologue: stage chunks 0 and 1 (12 outstanding loads/wave);
    // x-load + LN2 below hides their latency.
    stage_frag(imgMlp,         sW[0], 24, wv, lane);
    stage_frag(imgMlp + 12288, sW[1], 24, wv, lane);

    // ---- x load + LN2 entirely in registers (row wv*16+lr) ----
    s8v xreg[6];
    {
        const int row = rowbase + wv * 16 + lr;
        float4 xa[12];
        #pragma unroll
        for (int ks = 0; ks < 6; ++ks) {
            int k0 = 32 * ks + 8 * g;
            xa[2 * ks]     = *(const float4*)(xio + row * 192 + k0);
            xa[2 * ks + 1] = *(const float4*)(xio + row * 192 + k0 + 4);
        }
        float s = 0, sq = 0;
        #pragma unroll
        for (int i = 0; i < 12; ++i) {
            const float* p = &xa[i].x;
            #pragma unroll
            for (int e = 0; e < 4; ++e) { s += p[e]; sq += p[e] * p[e]; }
        }
        s += __shfl_xor(s, 16);  s += __shfl_xor(s, 32);
        sq += __shfl_xor(sq, 16); sq += __shfl_xor(sq, 32);
        float mu = s * (1.f / 192.f), var = sq * (1.f / 192.f) - mu * mu;
        float rs = rsqrtf(var + 1e-5f);
        #pragma unroll
        for (int ks = 0; ks < 6; ++ks) {
            H8 xa8;
            #pragma unroll
            for (int half = 0; half < 2; ++half) {
                int k0 = 32 * ks + 8 * g + 4 * half;
                float4 gg = *(const float4*)(g2 + k0);
                float4 be = *(const float4*)(be2 + k0);
                const float* p = &xa[2 * ks + half].x;
                const float* gp = &gg.x;
                const float* bp = &be.x;
                #pragma unroll
                for (int e = 0; e < 4; ++e)
                    xa8.h[4 * half + e] = f2b((p[e] - mu) * rs * gp[e] + bp[e]);
            }
            xreg[ks] = xa8.v;
        }
    }

    f32x4 accC[12];
    #pragma unroll
    for (int nt = 0; nt < 12; ++nt) accC[nt] = (f32x4){0.f, 0.f, 0.f, 0.f};

    const int s0lane = ((g & 1) * 2) * 16 + lr;     // shuffle sources
    const int s1lane = s0lane + 16;
    const bool hiHalf = (g >= 2);                   // nt2 = g>>1

    for (int ch = 0; ch < 24; ++ch) {
        // counted wait: ch's 6 loads landed; ch+1's 6 stay in flight (T4).
        if (ch < 23) asm volatile("s_waitcnt vmcnt(6)" ::: "memory");
        else         asm volatile("s_waitcnt vmcnt(0)" ::: "memory");
        __builtin_amdgcn_sched_barrier(0);
        __builtin_amdgcn_s_barrier();           // all waves' ch-loads landed
        __builtin_amdgcn_sched_barrier(0);
        const bf16* wc = sW[ch & 1];

        // ---- GEMM1 swapped: H^T = W1c^T . X^T ----
        f32x4 accHT[2];
        accHT[0] = (f32x4){0.f, 0.f, 0.f, 0.f};
        accHT[1] = (f32x4){0.f, 0.f, 0.f, 0.f};
        #pragma unroll
        for (int ks = 0; ks < 6; ++ks) {
            s8v w0 = *(const s8v*)(wc + ((ks * 2 + 0) * 64 + lane) * 8);
            s8v w1 = *(const s8v*)(wc + ((ks * 2 + 1) * 64 + lane) * 8);
            accHT[0] = __builtin_amdgcn_mfma_f32_16x16x32_bf16(w0, xreg[ks], accHT[0], 0, 0, 0);
            accHT[1] = __builtin_amdgcn_mfma_f32_16x16x32_bf16(w1, xreg[ks], accHT[1], 0, 0, 0);
        }

        // ---- gelu + pack at source lane, then in-wave shuffle to A-frag layout ----
        s8v aH;
        {
            unsigned int pk[2][2];          // [nt2][pair]
            #pragma unroll
            for (int nt2 = 0; nt2 < 2; ++nt2) {
                float4 b1v = *(const float4*)(b1 + ch * 32 + nt2 * 16 + 4 * g);
                const float* bp = &b1v.x;
                H4 t;
                #pragma unroll
                for (int e = 0; e < 4; ++e)
                    t.h[e] = f2b(gelu_f(accHT[nt2][e] + bp[e]));
                pk[nt2][0] = t.u[0];
                pk[nt2][1] = t.u[1];
            }
            U4V o;
            int a00 = __shfl((int)pk[0][0], s0lane), a10 = __shfl((int)pk[1][0], s0lane);
            int a01 = __shfl((int)pk[0][1], s0lane), a11 = __shfl((int)pk[1][1], s0lane);
            int b00 = __shfl((int)pk[0][0], s1lane), b10 = __shfl((int)pk[1][0], s1lane);
            int b01 = __shfl((int)pk[0][1], s1lane), b11 = __shfl((int)pk[1][1], s1lane);
            o.u[0] = (unsigned int)(hiHalf ? a10 : a00);
            o.u[1] = (unsigned int)(hiHalf ? a11 : a01);
            o.u[2] = (unsigned int)(hiHalf ? b10 : b00);
            o.u[3] = (unsigned int)(hiHalf ? b11 : b01);
            aH = o.v;
        }

        // ---- GEMM2: accC += H(64x32) . W2chunk(32x192) ----
        #pragma unroll
        for (int nt = 0; nt < 12; ++nt) {
            s8v bW = *(const s8v*)(wc + 6144 + (nt * 64 + lane) * 8);
            accC[nt] = __builtin_amdgcn_mfma_f32_16x16x32_bf16(aH, bW, accC[nt], 0, 0, 0);
        }

        __builtin_amdgcn_sched_barrier(0);
        __builtin_amdgcn_s_barrier();           // all waves done reading sW[ch&1]
        __builtin_amdgcn_sched_barrier(0);
        if (ch < 22)
            stage_frag(imgMlp + (ch + 2) * 12288, sW[ch & 1], 24, wv, lane);
    }

    // ---- epilogue: out = x + accC + b2 (in place, f32) ----
    #pragma unroll
    for (int nt = 0; nt < 12; ++nt) {
        int col = nt * 16 + lr;
        float bb = b2[col];
        #pragma unroll
        for (int e = 0; e < 4; ++e) {
            int row = rowbase + wv * 16 + g * 4 + e;
            float* p = xio + row * 192 + col;
            *p = accC[nt][e] + bb + *p;
        }
    }
}

extern "C" void kernel_launch(void* const* d_in, const int* in_sizes, int n_in,
                              void* d_out, int out_size, void* d_ws, size_t ws_size,
                              hipStream_t stream) {
    const float* skip   = (const float*)d_in[0];
    const float* xup    = (const float*)d_in[1];
    const float* g1     = (const float*)d_in[2];
    const float* be1    = (const float*)d_in[3];
    const float* g2     = (const float*)d_in[4];
    const float* be2    = (const float*)d_in[5];
    const float* Wkv    = (const float*)d_in[6];
    const float* bkv    = (const float*)d_in[7];
    const float* Wproj  = (const float*)d_in[8];
    const float* bproj  = (const float*)d_in[9];
    const float* btab   = (const float*)d_in[10];
    const int*  relidx  = (const int*)d_in[11];
    const float* W1     = (const float*)d_in[12];
    const float* b1     = (const float*)d_in[13];
    const float* W2     = (const float*)d_in[14];
    const float* b2     = (const float*)d_in[15];
    float* xio = (float*)d_out;          // x lives in d_out; k_mlp updates it in place
    bf16* ws = (bf16*)d_ws;              // weight images (~811 KB)

    k_prep<<<198, 256, 0, stream>>>(Wkv, Wproj, W1, W2, ws);
    k_attn<<<4096, 256, 0, stream>>>(skip, xup, g1, be1, ws, bkv,
                                     ws + 73728, bproj, btab, relidx, xio);
    k_mlp<<<4096, 256, 0, stream>>>(xio, g2, be2, ws + 110592, b1, b2);
}

// Round 17
// 564.421 us; speedup vs baseline: 1.0353x; 1.0353x over previous
//
#include <hip/hip_runtime.h>
#include <hip/hip_bf16.h>

typedef __hip_bfloat16 bf16;
typedef short s8v __attribute__((ext_vector_type(8)));   // 8 bf16 (4 VGPRs)
typedef float f32x4 __attribute__((ext_vector_type(4)));

__device__ __forceinline__ float b2f(bf16 v) { return __bfloat162float(v); }
__device__ __forceinline__ bf16 f2b(float v) { return __float2bfloat16(v); }

union H8 { bf16 h[8]; s8v v; uint2 u2[2]; };
union H4 { bf16 h[4]; unsigned int u[2]; };
union U4V { unsigned int u[4]; s8v v; };

// tanh-approx gelu in sigmoid form: 0.5x(1+tanh(y)) == x*sigmoid(2y)
__device__ __forceinline__ float gelu_f(float x) {
    float x2 = x * x;
    float t = fmaf(x2, 0.044715f, 1.0f);
    float u = x * 1.5957691216057308f * t;
    float e = __expf(-u);
    return x / (1.0f + e);
}

// async stage: copy nseg*1024B of fragment-linear image into LDS (linear dest)
__device__ __forceinline__ void stage_frag(const bf16* __restrict__ img, bf16* lds,
                                           int nseg, int wv, int lane) {
    for (int seg = wv; seg < nseg; seg += 4) {
        __builtin_amdgcn_global_load_lds(
            (const __attribute__((address_space(1))) void*)(img + seg * 512 + (lane << 3)),
            (__attribute__((address_space(3))) void*)(lds + seg * 512),
            16, 0, 0);
    }
}

// ---------------------------------------------------------------------------
// k_prep: build fragment-linear bf16 weight images in ws (unchanged).
// frag(lane,e) = W[k + e][n], k = tileK + (lane>>4)*8, n = tileN + (lane&15)
// ---------------------------------------------------------------------------
__global__ __launch_bounds__(256) void k_prep(
    const float* __restrict__ Wkv, const float* __restrict__ Wproj,
    const float* __restrict__ W1,  const float* __restrict__ W2,
    bf16* __restrict__ ws)
{
    int t = blockIdx.x * 256 + threadIdx.x;
    if (t >= 50688) return;
    int k, n, ld;
    const float* W;
    bf16* dst;
    if (t < 9216) {                 // Wkv
        int c = t / 1152, r = t % 1152;
        int tile = r >> 6, lane = r & 63;
        int ks = tile / 3, nt = tile % 3;
        n = c * 48 + nt * 16 + (lane & 15);
        k = ks * 32 + (lane >> 4) * 8;
        W = Wkv; ld = 384; dst = ws + t * 8;
    } else if (t < 13824) {         // Wproj
        int t2 = t - 9216;
        int c = t2 / 1152, r = t2 % 1152;
        int tile = r >> 6, lane = r & 63;
        int ks = tile / 3, nt = tile % 3;
        n = c * 48 + nt * 16 + (lane & 15);
        k = ks * 32 + (lane >> 4) * 8;
        W = Wproj; ld = 192; dst = ws + 73728 + t2 * 8;
    } else {                        // W1 / W2
        int t3 = t - 13824;
        int c = t3 / 1536, r = t3 % 1536;
        int half = r / 768, rr = r % 768;
        int tile = rr >> 6, lane = rr & 63;
        int lr = lane & 15, g = lane >> 4;
        if (half == 0) {            // W1[k][n0+n]
            int ks = tile >> 1, nt2 = tile & 1;
            n = c * 32 + nt2 * 16 + lr; k = ks * 32 + g * 8; W = W1; ld = 768;
        } else {                    // W2[n0+k][n]
            n = tile * 16 + lr; k = c * 32 + g * 8; W = W2; ld = 192;
        }
        dst = ws + 110592 + t3 * 8;
    }
    #pragma unroll
    for (int e = 0; e < 8; ++e) dst[e] = f2b(W[(k + e) * ld + n]);
}

// ---------------------------------------------------------------------------
// k_fused: per-window  LN1 -> kv -> attention -> proj(+skip, in regs) ->
//          LN2(in regs) -> MLP -> out.   x NEVER touches global memory.
// grid = 4096 windows, block = 256 (4 waves).  LDS = 70696 B (2 blocks/CU).
// ---------------------------------------------------------------------------
__global__ __launch_bounds__(256, 2) void k_fused(
    const float* __restrict__ skip, const float* __restrict__ xup,
    const float* __restrict__ g1,   const float* __restrict__ be1,
    const bf16*  __restrict__ imgKv,const float* __restrict__ bkv,
    const bf16*  __restrict__ imgPr,const float* __restrict__ bproj,
    const float* __restrict__ btab, const int*  __restrict__ relidx,
    const float* __restrict__ g2,   const float* __restrict__ be2,
    const bf16*  __restrict__ imgMlp,
    const float* __restrict__ b1,   const float* __restrict__ b2,
    float* __restrict__ out)
{
    __shared__ __align__(16) bf16 sK[64 * 200];      // K tile; later sX (xln bf16)
    __shared__ __align__(16) char poolRaw[36864];    // sVt+sP -> sO -> sW (MLP chunk)
    __shared__ __align__(16) float sBt[2058];        // staged bias table

    bf16* sVt = (bf16*)poolRaw;                // [192][72]  V^T
    bf16* sP  = (bf16*)(poolRaw + 27648);      // [64][72]   P (wave-private rows)
    bf16* sO  = (bf16*)poolRaw;                // [64][200]  attention output
    bf16* sX  = sK;                            // [64][200]  xln (after attn)
    bf16* sW  = (bf16*)poolRaw;                // [12288]    MLP weight chunk

    const int tid = threadIdx.x;
    const int lane = tid & 63;
    const int wv = tid >> 6;
    const int g = lane >> 4;        // k-group
    const int lr = lane & 15;       // A-row / B-col within 16-tile
    const int w = blockIdx.x;
    const int b = w >> 11;
    const int widx = w & 2047;
    const int d0 = widx >> 8, h0 = (widx >> 4) & 15, w0 = widx & 15;

    #define GROW(t) (b * 131072 + (d0 * 4 + ((t) >> 4)) * 4096 + \
                     (h0 * 4 + (((t) >> 2) & 3)) * 64 + (w0 * 4 + ((t) & 3)))

    // ================= Phase A: load + LN1 in registers =================
    const int myrow = wv * 16 + lr;
    const int growA = GROW(myrow) * 192;
    float4 u4[12], s4[12];
    #pragma unroll
    for (int ks = 0; ks < 6; ++ks) {
        int k0 = 32 * ks + 8 * g;
        u4[2 * ks]     = *(const float4*)(xup  + growA + k0);
        u4[2 * ks + 1] = *(const float4*)(xup  + growA + k0 + 4);
        s4[2 * ks]     = *(const float4*)(skip + growA + k0);
        s4[2 * ks + 1] = *(const float4*)(skip + growA + k0 + 4);
    }
    float su = 0, squ = 0, ss = 0, sqs = 0;
    #pragma unroll
    for (int i = 0; i < 12; ++i) {
        const float* up = &u4[i].x;
        const float* sp = &s4[i].x;
        #pragma unroll
        for (int e = 0; e < 4; ++e) {
            su += up[e]; squ += up[e] * up[e];
            ss += sp[e]; sqs += sp[e] * sp[e];
        }
    }
    su += __shfl_xor(su, 16);  su += __shfl_xor(su, 32);
    squ += __shfl_xor(squ, 16); squ += __shfl_xor(squ, 32);
    ss += __shfl_xor(ss, 16);  ss += __shfl_xor(ss, 32);
    sqs += __shfl_xor(sqs, 16); sqs += __shfl_xor(sqs, 32);
    const float inv192 = 1.f / 192.f;
    float muU = su * inv192, vU = squ * inv192 - muU * muU;
    float muS = ss * inv192, vS = sqs * inv192 - muS * muS;
    float rU = rsqrtf(vU + 1e-5f), rS = rsqrtf(vS + 1e-5f);
    const float scale = 0.17677669529663687f;   // 32^-0.5 (folded into Q)

    s8v qreg[6], sreg[6];
    #pragma unroll
    for (int ks = 0; ks < 6; ++ks) {
        H8 qa, sa;
        #pragma unroll
        for (int half = 0; half < 2; ++half) {
            const float* up = &u4[2 * ks + half].x;
            const float* sp = &s4[2 * ks + half].x;
            #pragma unroll
            for (int e = 0; e < 4; ++e) {
                int k = 32 * ks + 8 * g + 4 * half + e;
                float gg = g1[k], bb = be1[k];
                qa.h[4 * half + e] = f2b(((up[e] - muU) * rU * gg + bb) * scale);
                sa.h[4 * half + e] = f2b((sp[e] - muS) * rS * gg + bb);
            }
        }
        qreg[ks] = qa.v; sreg[ks] = sa.v;
    }

    // stage bias table into LDS (read after barrier 1)
    for (int i = tid; i < 2058; i += 256) sBt[i] = btab[i];

    // ================= Phase B: kv GEMM, B-frags from global =================
    for (int nc = 0; nc < 8; ++nc) {
        const bf16* img = imgKv + nc * 9216;
        f32x4 acc[3];
        #pragma unroll
        for (int nt = 0; nt < 3; ++nt) acc[nt] = (f32x4){0.f, 0.f, 0.f, 0.f};
        #pragma unroll
        for (int ks = 0; ks < 6; ++ks) {
            #pragma unroll
            for (int nt = 0; nt < 3; ++nt) {
                s8v bfr = *(const s8v*)(img + ((ks * 3 + nt) * 64 + lane) * 8);
                acc[nt] = __builtin_amdgcn_mfma_f32_16x16x32_bf16(sreg[ks], bfr, acc[nt], 0, 0, 0);
            }
        }
        if (nc < 4) {             // K columns -> sK[token][c]
            #pragma unroll
            for (int nt = 0; nt < 3; ++nt) {
                int c = nc * 48 + nt * 16 + lr;
                float bias = bkv[c];
                #pragma unroll
                for (int e = 0; e < 4; ++e)
                    sK[(wv * 16 + 4 * g + e) * 200 + c] = f2b(acc[nt][e] + bias);
            }
        } else {                  // V columns -> transposed sVt[d][token] (packed)
            #pragma unroll
            for (int nt = 0; nt < 3; ++nt) {
                int c = nc * 48 + nt * 16 + lr;
                float bias = bkv[c];
                int d = c - 192;
                H8 t4;
                #pragma unroll
                for (int e = 0; e < 4; ++e) t4.h[e] = f2b(acc[nt][e] + bias);
                *(uint2*)(sVt + d * 72 + wv * 16 + 4 * g) = t4.u2[0];
            }
        }
    }

    int bidx[4][4];
    #pragma unroll
    for (int nt = 0; nt < 4; ++nt)
        #pragma unroll
        for (int e = 0; e < 4; ++e)
            bidx[nt][e] = relidx[(wv * 16 + lr) * 64 + nt * 16 + 4 * g + e] * 6;

    __syncthreads();   // BARRIER 1: sK/sVt/sBt visible

    // ================= Phase C: attention per head =================
    f32x4 accOT[6][2];
    #pragma unroll
    for (int h = 0; h < 6; ++h)
        #pragma unroll
        for (int nt = 0; nt < 2; ++nt) accOT[h][nt] = (f32x4){0.f, 0.f, 0.f, 0.f};

    #pragma unroll
    for (int h = 0; h < 6; ++h) {
        f32x4 s[4];
        #pragma unroll
        for (int nt = 0; nt < 4; ++nt) {
            s8v kf = *(const s8v*)(sK + (nt * 16 + lr) * 200 + h * 32 + 8 * g);
            s[nt] = __builtin_amdgcn_mfma_f32_16x16x32_bf16(kf, qreg[h],
                        (f32x4){0.f, 0.f, 0.f, 0.f}, 0, 0, 0);
        }
        #pragma unroll
        for (int nt = 0; nt < 4; ++nt)
            #pragma unroll
            for (int e = 0; e < 4; ++e)
                s[nt][e] += sBt[bidx[nt][e] + h];
        float mx = -1e30f;
        #pragma unroll
        for (int nt = 0; nt < 4; ++nt)
            #pragma unroll
            for (int e = 0; e < 4; ++e) mx = fmaxf(mx, s[nt][e]);
        mx = fmaxf(mx, __shfl_xor(mx, 16));
        mx = fmaxf(mx, __shfl_xor(mx, 32));
        float sm = 0;
        #pragma unroll
        for (int nt = 0; nt < 4; ++nt)
            #pragma unroll
            for (int e = 0; e < 4; ++e) { s[nt][e] = __expf(s[nt][e] - mx); sm += s[nt][e]; }
        sm += __shfl_xor(sm, 16);
        sm += __shfl_xor(sm, 32);
        float iv = 1.f / sm;
        #pragma unroll
        for (int nt = 0; nt < 4; ++nt) {
            H8 pk;
            #pragma unroll
            for (int e = 0; e < 4; ++e) pk.h[e] = f2b(s[nt][e] * iv);
            *(uint2*)(sP + (wv * 16 + lr) * 72 + nt * 16 + 4 * g) = pk.u2[0];
        }
        s8v aP0 = *(const s8v*)(sP + (wv * 16 + lr) * 72 + 8 * g);
        s8v aP1 = *(const s8v*)(sP + (wv * 16 + lr) * 72 + 32 + 8 * g);
        #pragma unroll
        for (int nt = 0; nt < 2; ++nt) {
            const bf16* vb = sVt + (h * 32 + nt * 16 + lr) * 72;
            s8v v0 = *(const s8v*)(vb + 8 * g);
            s8v v1 = *(const s8v*)(vb + 32 + 8 * g);
            accOT[h][nt] = __builtin_amdgcn_mfma_f32_16x16x32_bf16(v0, aP0, accOT[h][nt], 0, 0, 0);
            accOT[h][nt] = __builtin_amdgcn_mfma_f32_16x16x32_bf16(v1, aP1, accOT[h][nt], 0, 0, 0);
        }
    }

    __syncthreads();   // BARRIER 2: PV reads of sVt/sP done -> sO may overwrite

    // ---- spill O (packed, wave-private rows) and reload as A-frags ----
    #pragma unroll
    for (int h = 0; h < 6; ++h)
        #pragma unroll
        for (int nt = 0; nt < 2; ++nt) {
            H8 pk;
            #pragma unroll
            for (int e = 0; e < 4; ++e) pk.h[e] = f2b(accOT[h][nt][e]);
            *(uint2*)(sO + (wv * 16 + lr) * 200 + h * 32 + nt * 16 + 4 * g) = pk.u2[0];
        }
    s8v aO[6];
    #pragma unroll
    for (int ks = 0; ks < 6; ++ks)
        aO[ks] = *(const s8v*)(sO + (wv * 16 + lr) * 200 + 32 * ks + 8 * g);

    // ================= Phase D: proj + skip, x kept in registers ==========
    int gq[4];
    #pragma unroll
    for (int e = 0; e < 4; ++e) gq[e] = GROW(wv * 16 + 4 * g + e) * 192;

    float xf[12][4];   // x[row = wv*16+4g+e][col = nt*16+lr], nt = nc*3+nt3
    for (int nc = 0; nc < 4; ++nc) {
        const bf16* img = imgPr + nc * 9216;
        f32x4 acc[3];
        #pragma unroll
        for (int nt = 0; nt < 3; ++nt) acc[nt] = (f32x4){0.f, 0.f, 0.f, 0.f};
        #pragma unroll
        for (int ks = 0; ks < 6; ++ks) {
            #pragma unroll
            for (int nt = 0; nt < 3; ++nt) {
                s8v bfr = *(const s8v*)(img + ((ks * 3 + nt) * 64 + lane) * 8);
                acc[nt] = __builtin_amdgcn_mfma_f32_16x16x32_bf16(aO[ks], bfr, acc[nt], 0, 0, 0);
            }
        }
        #pragma unroll
        for (int nt3 = 0; nt3 < 3; ++nt3) {
            int c = nc * 48 + nt3 * 16 + lr;
            float bp = bproj[c];
            #pragma unroll
            for (int e = 0; e < 4; ++e)
                xf[nc * 3 + nt3][e] = acc[nt3][e] + bp + skip[gq[e] + c];
        }
    }

    // ---- LN2 in registers (stats over 12 local + 16 lr-lanes) ----
    #pragma unroll
    for (int e = 0; e < 4; ++e) {
        float s = 0, sq = 0;
        #pragma unroll
        for (int j = 0; j < 12; ++j) { s += xf[j][e]; sq += xf[j][e] * xf[j][e]; }
        s += __shfl_xor(s, 1); s += __shfl_xor(s, 2);
        s += __shfl_xor(s, 4); s += __shfl_xor(s, 8);
        sq += __shfl_xor(sq, 1); sq += __shfl_xor(sq, 2);
        sq += __shfl_xor(sq, 4); sq += __shfl_xor(sq, 8);
        float mu = s * (1.f / 192.f), var = sq * (1.f / 192.f) - mu * mu;
        float rs = rsqrtf(var + 1e-5f);
        int row = wv * 16 + 4 * g + e;
        #pragma unroll
        for (int j = 0; j < 12; ++j) {
            int c = j * 16 + lr;
            sX[row * 200 + c] = f2b((xf[j][e] - mu) * rs * g2[c] + be2[c]);
        }
    }

    __syncthreads();   // BARRIER 3: all sO reads done (pool free for sW); sX complete

    // ---- xln B-frags (row = wv*16+lr) ----
    s8v xreg[6];
    #pragma unroll
    for (int ks = 0; ks < 6; ++ks)
        xreg[ks] = *(const s8v*)(sX + (wv * 16 + lr) * 200 + 32 * ks + 8 * g);

    // ================= MLP: 24 hidden-chunks of 32 =================
    f32x4 accC[12];
    #pragma unroll
    for (int nt = 0; nt < 12; ++nt) accC[nt] = (f32x4){0.f, 0.f, 0.f, 0.f};

    const int s0lane = ((g & 1) * 2) * 16 + lr;     // shuffle sources
    const int s1lane = s0lane + 16;
    const bool hiHalf = (g >= 2);                   // nt2 = g>>1

    for (int ch = 0; ch < 24; ++ch) {
        stage_frag(imgMlp + ch * 12288, sW, 24, wv, lane);
        __syncthreads();    // staged (vmcnt drained)

        // ---- GEMM1 swapped: H^T = W1c^T . X^T ----
        f32x4 accHT[2];
        accHT[0] = (f32x4){0.f, 0.f, 0.f, 0.f};
        accHT[1] = (f32x4){0.f, 0.f, 0.f, 0.f};
        #pragma unroll
        for (int ks = 0; ks < 6; ++ks) {
            s8v w0 = *(const s8v*)(sW + ((ks * 2 + 0) * 64 + lane) * 8);
            s8v w1 = *(const s8v*)(sW + ((ks * 2 + 1) * 64 + lane) * 8);
            accHT[0] = __builtin_amdgcn_mfma_f32_16x16x32_bf16(w0, xreg[ks], accHT[0], 0, 0, 0);
            accHT[1] = __builtin_amdgcn_mfma_f32_16x16x32_bf16(w1, xreg[ks], accHT[1], 0, 0, 0);
        }

        // ---- gelu + pack, in-wave shuffle to A-frag layout ----
        s8v aH;
        {
            unsigned int pk[2][2];
            #pragma unroll
            for (int nt2 = 0; nt2 < 2; ++nt2) {
                float4 b1v = *(const float4*)(b1 + ch * 32 + nt2 * 16 + 4 * g);
                const float* bp = &b1v.x;
                H4 t;
                #pragma unroll
                for (int e = 0; e < 4; ++e)
                    t.h[e] = f2b(gelu_f(accHT[nt2][e] + bp[e]));
                pk[nt2][0] = t.u[0];
                pk[nt2][1] = t.u[1];
            }
            U4V o;
            int a00 = __shfl((int)pk[0][0], s0lane), a10 = __shfl((int)pk[1][0], s0lane);
            int a01 = __shfl((int)pk[0][1], s0lane), a11 = __shfl((int)pk[1][1], s0lane);
            int b00 = __shfl((int)pk[0][0], s1lane), b10 = __shfl((int)pk[1][0], s1lane);
            int b01 = __shfl((int)pk[0][1], s1lane), b11 = __shfl((int)pk[1][1], s1lane);
            o.u[0] = (unsigned int)(hiHalf ? a10 : a00);
            o.u[1] = (unsigned int)(hiHalf ? a11 : a01);
            o.u[2] = (unsigned int)(hiHalf ? b10 : b00);
            o.u[3] = (unsigned int)(hiHalf ? b11 : b01);
            aH = o.v;
        }

        // ---- GEMM2: accC += H(64x32) . W2chunk(32x192) ----
        #pragma unroll
        for (int nt = 0; nt < 12; ++nt) {
            s8v bW = *(const s8v*)(sW + 6144 + (nt * 64 + lane) * 8);
            accC[nt] = __builtin_amdgcn_mfma_f32_16x16x32_bf16(aH, bW, accC[nt], 0, 0, 0);
        }
        __syncthreads();    // reads of sW done -> safe to restage
    }

    // ---- epilogue: out = x + accC + b2 (pure store; x was in regs) ----
    #pragma unroll
    for (int nt = 0; nt < 12; ++nt) {
        int c = nt * 16 + lr;
        float bb = b2[c];
        #pragma unroll
        for (int e = 0; e < 4; ++e)
            out[gq[e] + c] = xf[nt][e] + accC[nt][e] + bb;
    }
    #undef GROW
}

extern "C" void kernel_launch(void* const* d_in, const int* in_sizes, int n_in,
                              void* d_out, int out_size, void* d_ws, size_t ws_size,
                              hipStream_t stream) {
    const float* skip   = (const float*)d_in[0];
    const float* xup    = (const float*)d_in[1];
    const float* g1     = (const float*)d_in[2];
    const float* be1    = (const float*)d_in[3];
    const float* g2     = (const float*)d_in[4];
    const float* be2    = (const float*)d_in[5];
    const float* Wkv    = (const float*)d_in[6];
    const float* bkv    = (const float*)d_in[7];
    const float* Wproj  = (const float*)d_in[8];
    const float* bproj  = (const float*)d_in[9];
    const float* btab   = (const float*)d_in[10];
    const int*  relidx  = (const int*)d_in[11];
    const float* W1     = (const float*)d_in[12];
    const float* b1     = (const float*)d_in[13];
    const float* W2     = (const float*)d_in[14];
    const float* b2     = (const float*)d_in[15];
    bf16* ws = (bf16*)d_ws;              // weight images (~811 KB)

    k_prep<<<198, 256, 0, stream>>>(Wkv, Wproj, W1, W2, ws);
    k_fused<<<4096, 256, 0, stream>>>(skip, xup, g1, be1, ws, bkv,
                                      ws + 73728, bproj, btab, relidx,
                                      g2, be2, ws + 110592, b1, b2,
                                      (float*)d_out);
}

// Round 18
// 542.837 us; speedup vs baseline: 1.0765x; 1.0398x over previous
//
#include <hip/hip_runtime.h>
#include <hip/hip_bf16.h>

typedef __hip_bfloat16 bf16;
typedef short s8v __attribute__((ext_vector_type(8)));   // 8 bf16 (4 VGPRs)
typedef float f32x4 __attribute__((ext_vector_type(4)));

__device__ __forceinline__ float b2f(bf16 v) { return __bfloat162float(v); }
__device__ __forceinline__ bf16 f2b(float v) { return __float2bfloat16(v); }

union H8 { bf16 h[8]; s8v v; uint2 u2[2]; };
union H4 { bf16 h[4]; unsigned int u[2]; };
union U4V { unsigned int u[4]; s8v v; };

// tanh-approx gelu in sigmoid form: 0.5x(1+tanh(y)) == x*sigmoid(2y)
__device__ __forceinline__ float gelu_f(float x) {
    float x2 = x * x;
    float t = fmaf(x2, 0.044715f, 1.0f);
    float u = x * 1.5957691216057308f * t;
    float e = __expf(-u);
    return x / (1.0f + e);
}

// async stage: copy nseg*1024B of fragment-linear image into LDS (linear dest)
__device__ __forceinline__ void stage_frag(const bf16* __restrict__ img, bf16* lds,
                                           int nseg, int wv, int lane) {
    for (int seg = wv; seg < nseg; seg += 4) {
        __builtin_amdgcn_global_load_lds(
            (const __attribute__((address_space(1))) void*)(img + seg * 512 + (lane << 3)),
            (__attribute__((address_space(3))) void*)(lds + seg * 512),
            16, 0, 0);
    }
}

// ---------------------------------------------------------------------------
// k_prep: build fragment-linear bf16 weight images in ws (unchanged).
// frag(lane,e) = W[k + e][n], k = tileK + (lane>>4)*8, n = tileN + (lane&15)
// ---------------------------------------------------------------------------
__global__ __launch_bounds__(256) void k_prep(
    const float* __restrict__ Wkv, const float* __restrict__ Wproj,
    const float* __restrict__ W1,  const float* __restrict__ W2,
    bf16* __restrict__ ws)
{
    int t = blockIdx.x * 256 + threadIdx.x;
    if (t >= 50688) return;
    int k, n, ld;
    const float* W;
    bf16* dst;
    if (t < 9216) {                 // Wkv
        int c = t / 1152, r = t % 1152;
        int tile = r >> 6, lane = r & 63;
        int ks = tile / 3, nt = tile % 3;
        n = c * 48 + nt * 16 + (lane & 15);
        k = ks * 32 + (lane >> 4) * 8;
        W = Wkv; ld = 384; dst = ws + t * 8;
    } else if (t < 13824) {         // Wproj
        int t2 = t - 9216;
        int c = t2 / 1152, r = t2 % 1152;
        int tile = r >> 6, lane = r & 63;
        int ks = tile / 3, nt = tile % 3;
        n = c * 48 + nt * 16 + (lane & 15);
        k = ks * 32 + (lane >> 4) * 8;
        W = Wproj; ld = 192; dst = ws + 73728 + t2 * 8;
    } else {                        // W1 / W2
        int t3 = t - 13824;
        int c = t3 / 1536, r = t3 % 1536;
        int half = r / 768, rr = r % 768;
        int tile = rr >> 6, lane = rr & 63;
        int lr = lane & 15, g = lane >> 4;
        if (half == 0) {            // W1[k][n0+n]
            int ks = tile >> 1, nt2 = tile & 1;
            n = c * 32 + nt2 * 16 + lr; k = ks * 32 + g * 8; W = W1; ld = 768;
        } else {                    // W2[n0+k][n]
            n = tile * 16 + lr; k = c * 32 + g * 8; W = W2; ld = 192;
        }
        dst = ws + 110592 + t3 * 8;
    }
    #pragma unroll
    for (int e = 0; e < 8; ++e) dst[e] = f2b(W[(k + e) * ld + n]);
}

// ---------------------------------------------------------------------------
// k_fused: per-window  LN1 -> kv -> attention -> proj(+skip, in regs) ->
//          LN2(in regs) -> MLP (dbuf counted-vmcnt) -> out.
// grid = 4096 windows, block = 256 (4 waves).  LDS = 70696 B (2 blocks/CU).
// ---------------------------------------------------------------------------
__global__ __launch_bounds__(256, 2) void k_fused(
    const float* __restrict__ skip, const float* __restrict__ xup,
    const float* __restrict__ g1,   const float* __restrict__ be1,
    const bf16*  __restrict__ imgKv,const float* __restrict__ bkv,
    const bf16*  __restrict__ imgPr,const float* __restrict__ bproj,
    const float* __restrict__ btab, const int*  __restrict__ relidx,
    const float* __restrict__ g2,   const float* __restrict__ be2,
    const bf16*  __restrict__ imgMlp,
    const float* __restrict__ b1,   const float* __restrict__ b2,
    float* __restrict__ out)
{
    __shared__ __align__(1024) bf16 sK[64 * 200];    // K tile; later sX; later sW buf 1
    __shared__ __align__(1024) char poolRaw[36864];  // sVt+sP -> sO -> sW buf 0
    __shared__ __align__(16) float sBt[2058];        // staged bias table

    bf16* sVt = (bf16*)poolRaw;                // [192][72]  V^T
    bf16* sP  = (bf16*)(poolRaw + 27648);      // [64][72]   P (wave-private rows)
    bf16* sO  = (bf16*)poolRaw;                // [64][200]  attention output
    bf16* sX  = sK;                            // [64][200]  xln (after attn)
    bf16* sW0 = (bf16*)poolRaw;                // [12288]    MLP chunk buf 0
    bf16* sW1 = sK;                            // [12288]    MLP chunk buf 1 (sX dead)

    const int tid = threadIdx.x;
    const int lane = tid & 63;
    const int wv = tid >> 6;
    const int g = lane >> 4;        // k-group
    const int lr = lane & 15;       // A-row / B-col within 16-tile
    const int w = blockIdx.x;
    const int b = w >> 11;
    const int widx = w & 2047;
    const int d0 = widx >> 8, h0 = (widx >> 4) & 15, w0 = widx & 15;

    #define GROW(t) (b * 131072 + (d0 * 4 + ((t) >> 4)) * 4096 + \
                     (h0 * 4 + (((t) >> 2) & 3)) * 64 + (w0 * 4 + ((t) & 3)))

    // ================= Phase A: load + LN1 in registers =================
    const int myrow = wv * 16 + lr;
    const int growA = GROW(myrow) * 192;
    float4 u4[12], s4[12];
    #pragma unroll
    for (int ks = 0; ks < 6; ++ks) {
        int k0 = 32 * ks + 8 * g;
        u4[2 * ks]     = *(const float4*)(xup  + growA + k0);
        u4[2 * ks + 1] = *(const float4*)(xup  + growA + k0 + 4);
        s4[2 * ks]     = *(const float4*)(skip + growA + k0);
        s4[2 * ks + 1] = *(const float4*)(skip + growA + k0 + 4);
    }
    float su = 0, squ = 0, ss = 0, sqs = 0;
    #pragma unroll
    for (int i = 0; i < 12; ++i) {
        const float* up = &u4[i].x;
        const float* sp = &s4[i].x;
        #pragma unroll
        for (int e = 0; e < 4; ++e) {
            su += up[e]; squ += up[e] * up[e];
            ss += sp[e]; sqs += sp[e] * sp[e];
        }
    }
    su += __shfl_xor(su, 16);  su += __shfl_xor(su, 32);
    squ += __shfl_xor(squ, 16); squ += __shfl_xor(squ, 32);
    ss += __shfl_xor(ss, 16);  ss += __shfl_xor(ss, 32);
    sqs += __shfl_xor(sqs, 16); sqs += __shfl_xor(sqs, 32);
    const float inv192 = 1.f / 192.f;
    float muU = su * inv192, vU = squ * inv192 - muU * muU;
    float muS = ss * inv192, vS = sqs * inv192 - muS * muS;
    float rU = rsqrtf(vU + 1e-5f), rS = rsqrtf(vS + 1e-5f);
    const float scale = 0.17677669529663687f;   // 32^-0.5 (folded into Q)

    s8v qreg[6], sreg[6];
    #pragma unroll
    for (int ks = 0; ks < 6; ++ks) {
        H8 qa, sa;
        #pragma unroll
        for (int half = 0; half < 2; ++half) {
            const float* up = &u4[2 * ks + half].x;
            const float* sp = &s4[2 * ks + half].x;
            #pragma unroll
            for (int e = 0; e < 4; ++e) {
                int k = 32 * ks + 8 * g + 4 * half + e;
                float gg = g1[k], bb = be1[k];
                qa.h[4 * half + e] = f2b(((up[e] - muU) * rU * gg + bb) * scale);
                sa.h[4 * half + e] = f2b((sp[e] - muS) * rS * gg + bb);
            }
        }
        qreg[ks] = qa.v; sreg[ks] = sa.v;
    }

    // stage bias table into LDS (read after barrier 1)
    for (int i = tid; i < 2058; i += 256) sBt[i] = btab[i];

    // ================= Phase B: kv GEMM, B-frags from global =================
    for (int nc = 0; nc < 8; ++nc) {
        const bf16* img = imgKv + nc * 9216;
        f32x4 acc[3];
        #pragma unroll
        for (int nt = 0; nt < 3; ++nt) acc[nt] = (f32x4){0.f, 0.f, 0.f, 0.f};
        #pragma unroll
        for (int ks = 0; ks < 6; ++ks) {
            #pragma unroll
            for (int nt = 0; nt < 3; ++nt) {
                s8v bfr = *(const s8v*)(img + ((ks * 3 + nt) * 64 + lane) * 8);
                acc[nt] = __builtin_amdgcn_mfma_f32_16x16x32_bf16(sreg[ks], bfr, acc[nt], 0, 0, 0);
            }
        }
        if (nc < 4) {             // K columns -> sK[token][c]
            #pragma unroll
            for (int nt = 0; nt < 3; ++nt) {
                int c = nc * 48 + nt * 16 + lr;
                float bias = bkv[c];
                #pragma unroll
                for (int e = 0; e < 4; ++e)
                    sK[(wv * 16 + 4 * g + e) * 200 + c] = f2b(acc[nt][e] + bias);
            }
        } else {                  // V columns -> transposed sVt[d][token] (packed)
            #pragma unroll
            for (int nt = 0; nt < 3; ++nt) {
                int c = nc * 48 + nt * 16 + lr;
                float bias = bkv[c];
                int d = c - 192;
                H8 t4;
                #pragma unroll
                for (int e = 0; e < 4; ++e) t4.h[e] = f2b(acc[nt][e] + bias);
                *(uint2*)(sVt + d * 72 + wv * 16 + 4 * g) = t4.u2[0];
            }
        }
    }

    int bidx[4][4];
    #pragma unroll
    for (int nt = 0; nt < 4; ++nt)
        #pragma unroll
        for (int e = 0; e < 4; ++e)
            bidx[nt][e] = relidx[(wv * 16 + lr) * 64 + nt * 16 + 4 * g + e] * 6;

    __syncthreads();   // BARRIER 1: sK/sVt/sBt visible

    // ================= Phase C: attention per head =================
    f32x4 accOT[6][2];
    #pragma unroll
    for (int h = 0; h < 6; ++h)
        #pragma unroll
        for (int nt = 0; nt < 2; ++nt) accOT[h][nt] = (f32x4){0.f, 0.f, 0.f, 0.f};

    #pragma unroll
    for (int h = 0; h < 6; ++h) {
        f32x4 s[4];
        #pragma unroll
        for (int nt = 0; nt < 4; ++nt) {
            s8v kf = *(const s8v*)(sK + (nt * 16 + lr) * 200 + h * 32 + 8 * g);
            s[nt] = __builtin_amdgcn_mfma_f32_16x16x32_bf16(kf, qreg[h],
                        (f32x4){0.f, 0.f, 0.f, 0.f}, 0, 0, 0);
        }
        #pragma unroll
        for (int nt = 0; nt < 4; ++nt)
            #pragma unroll
            for (int e = 0; e < 4; ++e)
                s[nt][e] += sBt[bidx[nt][e] + h];
        float mx = -1e30f;
        #pragma unroll
        for (int nt = 0; nt < 4; ++nt)
            #pragma unroll
            for (int e = 0; e < 4; ++e) mx = fmaxf(mx, s[nt][e]);
        mx = fmaxf(mx, __shfl_xor(mx, 16));
        mx = fmaxf(mx, __shfl_xor(mx, 32));
        float sm = 0;
        #pragma unroll
        for (int nt = 0; nt < 4; ++nt)
            #pragma unroll
            for (int e = 0; e < 4; ++e) { s[nt][e] = __expf(s[nt][e] - mx); sm += s[nt][e]; }
        sm += __shfl_xor(sm, 16);
        sm += __shfl_xor(sm, 32);
        float iv = 1.f / sm;
        #pragma unroll
        for (int nt = 0; nt < 4; ++nt) {
            H8 pk;
            #pragma unroll
            for (int e = 0; e < 4; ++e) pk.h[e] = f2b(s[nt][e] * iv);
            *(uint2*)(sP + (wv * 16 + lr) * 72 + nt * 16 + 4 * g) = pk.u2[0];
        }
        s8v aP0 = *(const s8v*)(sP + (wv * 16 + lr) * 72 + 8 * g);
        s8v aP1 = *(const s8v*)(sP + (wv * 16 + lr) * 72 + 32 + 8 * g);
        #pragma unroll
        for (int nt = 0; nt < 2; ++nt) {
            const bf16* vb = sVt + (h * 32 + nt * 16 + lr) * 72;
            s8v v0 = *(const s8v*)(vb + 8 * g);
            s8v v1 = *(const s8v*)(vb + 32 + 8 * g);
            accOT[h][nt] = __builtin_amdgcn_mfma_f32_16x16x32_bf16(v0, aP0, accOT[h][nt], 0, 0, 0);
            accOT[h][nt] = __builtin_amdgcn_mfma_f32_16x16x32_bf16(v1, aP1, accOT[h][nt], 0, 0, 0);
        }
    }

    __syncthreads();   // BARRIER 2: PV reads of sVt/sP done -> sO may overwrite

    // ---- spill O (packed, wave-private rows) and reload as A-frags ----
    #pragma unroll
    for (int h = 0; h < 6; ++h)
        #pragma unroll
        for (int nt = 0; nt < 2; ++nt) {
            H8 pk;
            #pragma unroll
            for (int e = 0; e < 4; ++e) pk.h[e] = f2b(accOT[h][nt][e]);
            *(uint2*)(sO + (wv * 16 + lr) * 200 + h * 32 + nt * 16 + 4 * g) = pk.u2[0];
        }
    s8v aO[6];
    #pragma unroll
    for (int ks = 0; ks < 6; ++ks)
        aO[ks] = *(const s8v*)(sO + (wv * 16 + lr) * 200 + 32 * ks + 8 * g);

    // ================= Phase D: proj + skip, x kept in registers ==========
    int gq[4];
    #pragma unroll
    for (int e = 0; e < 4; ++e) gq[e] = GROW(wv * 16 + 4 * g + e) * 192;

    float xf[12][4];   // x[row = wv*16+4g+e][col = nt*16+lr], nt = nc*3+nt3
    for (int nc = 0; nc < 4; ++nc) {
        const bf16* img = imgPr + nc * 9216;
        f32x4 acc[3];
        #pragma unroll
        for (int nt = 0; nt < 3; ++nt) acc[nt] = (f32x4){0.f, 0.f, 0.f, 0.f};
        #pragma unroll
        for (int ks = 0; ks < 6; ++ks) {
            #pragma unroll
            for (int nt = 0; nt < 3; ++nt) {
                s8v bfr = *(const s8v*)(img + ((ks * 3 + nt) * 64 + lane) * 8);
                acc[nt] = __builtin_amdgcn_mfma_f32_16x16x32_bf16(aO[ks], bfr, acc[nt], 0, 0, 0);
            }
        }
        #pragma unroll
        for (int nt3 = 0; nt3 < 3; ++nt3) {
            int c = nc * 48 + nt3 * 16 + lr;
            float bp = bproj[c];
            #pragma unroll
            for (int e = 0; e < 4; ++e)
                xf[nc * 3 + nt3][e] = acc[nt3][e] + bp + skip[gq[e] + c];
        }
    }

    // ---- LN2 in registers (stats over 12 local + 16 lr-lanes) ----
    #pragma unroll
    for (int e = 0; e < 4; ++e) {
        float s = 0, sq = 0;
        #pragma unroll
        for (int j = 0; j < 12; ++j) { s += xf[j][e]; sq += xf[j][e] * xf[j][e]; }
        s += __shfl_xor(s, 1); s += __shfl_xor(s, 2);
        s += __shfl_xor(s, 4); s += __shfl_xor(s, 8);
        sq += __shfl_xor(sq, 1); sq += __shfl_xor(sq, 2);
        sq += __shfl_xor(sq, 4); sq += __shfl_xor(sq, 8);
        float mu = s * (1.f / 192.f), var = sq * (1.f / 192.f) - mu * mu;
        float rs = rsqrtf(var + 1e-5f);
        int row = wv * 16 + 4 * g + e;
        #pragma unroll
        for (int j = 0; j < 12; ++j) {
            int c = j * 16 + lr;
            sX[row * 200 + c] = f2b((xf[j][e] - mu) * rs * g2[c] + be2[c]);
        }
    }

    __syncthreads();   // BARRIER 3: sO reads done; sX complete

    // ---- xln B-frags (row = wv*16+lr) ----
    s8v xreg[6];
    #pragma unroll
    for (int ks = 0; ks < 6; ++ks)
        xreg[ks] = *(const s8v*)(sX + (wv * 16 + lr) * 200 + 32 * ks + 8 * g);

    __syncthreads();   // BARRIER 4: all waves read sX -> sK region free for sW1

    // prologue: stage chunks 0 and 1 (12 outstanding loads/wave)
    stage_frag(imgMlp,         sW0, 24, wv, lane);
    stage_frag(imgMlp + 12288, sW1, 24, wv, lane);

    // ================= MLP: 24 hidden-chunks of 32, dbuf counted vmcnt ==========
    f32x4 accC[12];
    #pragma unroll
    for (int nt = 0; nt < 12; ++nt) accC[nt] = (f32x4){0.f, 0.f, 0.f, 0.f};

    const int s0lane = ((g & 1) * 2) * 16 + lr;     // shuffle sources
    const int s1lane = s0lane + 16;
    const bool hiHalf = (g >= 2);                   // nt2 = g>>1

    for (int ch = 0; ch < 24; ++ch) {
        // counted wait: ch's 6 loads landed; ch+1's 6 stay in flight (T4).
        if (ch < 23) asm volatile("s_waitcnt vmcnt(6)" ::: "memory");
        else         asm volatile("s_waitcnt vmcnt(0)" ::: "memory");
        __builtin_amdgcn_sched_barrier(0);
        __builtin_amdgcn_s_barrier();           // all waves' ch-loads landed
        __builtin_amdgcn_sched_barrier(0);
        const bf16* wc = (ch & 1) ? sW1 : sW0;

        // ---- GEMM1 swapped: H^T = W1c^T . X^T ----
        f32x4 accHT[2];
        accHT[0] = (f32x4){0.f, 0.f, 0.f, 0.f};
        accHT[1] = (f32x4){0.f, 0.f, 0.f, 0.f};
        #pragma unroll
        for (int ks = 0; ks < 6; ++ks) {
            s8v w0 = *(const s8v*)(wc + ((ks * 2 + 0) * 64 + lane) * 8);
            s8v w1 = *(const s8v*)(wc + ((ks * 2 + 1) * 64 + lane) * 8);
            accHT[0] = __builtin_amdgcn_mfma_f32_16x16x32_bf16(w0, xreg[ks], accHT[0], 0, 0, 0);
            accHT[1] = __builtin_amdgcn_mfma_f32_16x16x32_bf16(w1, xreg[ks], accHT[1], 0, 0, 0);
        }

        // ---- gelu + pack, in-wave shuffle to A-frag layout ----
        s8v aH;
        {
            unsigned int pk[2][2];
            #pragma unroll
            for (int nt2 = 0; nt2 < 2; ++nt2) {
                float4 b1v = *(const float4*)(b1 + ch * 32 + nt2 * 16 + 4 * g);
                const float* bp = &b1v.x;
                H4 t;
                #pragma unroll
                for (int e = 0; e < 4; ++e)
                    t.h[e] = f2b(gelu_f(accHT[nt2][e] + bp[e]));
                pk[nt2][0] = t.u[0];
                pk[nt2][1] = t.u[1];
            }
            U4V o;
            int a00 = __shfl((int)pk[0][0], s0lane), a10 = __shfl((int)pk[1][0], s0lane);
            int a01 = __shfl((int)pk[0][1], s0lane), a11 = __shfl((int)pk[1][1], s0lane);
            int b00 = __shfl((int)pk[0][0], s1lane), b10 = __shfl((int)pk[1][0], s1lane);
            int b01 = __shfl((int)pk[0][1], s1lane), b11 = __shfl((int)pk[1][1], s1lane);
            o.u[0] = (unsigned int)(hiHalf ? a10 : a00);
            o.u[1] = (unsigned int)(hiHalf ? a11 : a01);
            o.u[2] = (unsigned int)(hiHalf ? b10 : b00);
            o.u[3] = (unsigned int)(hiHalf ? b11 : b01);
            aH = o.v;
        }

        // ---- GEMM2: accC += H(64x32) . W2chunk(32x192) ----
        #pragma unroll
        for (int nt = 0; nt < 12; ++nt) {
            s8v bW = *(const s8v*)(wc + 6144 + (nt * 64 + lane) * 8);
            accC[nt] = __builtin_amdgcn_mfma_f32_16x16x32_bf16(aH, bW, accC[nt], 0, 0, 0);
        }

        __builtin_amdgcn_sched_barrier(0);
        __builtin_amdgcn_s_barrier();           // all waves done reading this buffer
        __builtin_amdgcn_sched_barrier(0);
        if (ch < 22)
            stage_frag(imgMlp + (ch + 2) * 12288, (ch & 1) ? sW1 : sW0, 24, wv, lane);
    }

    // ---- epilogue: out = x + accC + b2 (pure store; x was in regs) ----
    #pragma unroll
    for (int nt = 0; nt < 12; ++nt) {
        int c = nt * 16 + lr;
        float bb = b2[c];
        #pragma unroll
        for (int e = 0; e < 4; ++e)
            out[gq[e] + c] = xf[nt][e] + accC[nt][e] + bb;
    }
    #undef GROW
}

extern "C" void kernel_launch(void* const* d_in, const int* in_sizes, int n_in,
                              void* d_out, int out_size, void* d_ws, size_t ws_size,
                              hipStream_t stream) {
    const float* skip   = (const float*)d_in[0];
    const float* xup    = (const float*)d_in[1];
    const float* g1     = (const float*)d_in[2];
    const float* be1    = (const float*)d_in[3];
    const float* g2     = (const float*)d_in[4];
    const float* be2    = (const float*)d_in[5];
    const float* Wkv    = (const float*)d_in[6];
    const float* bkv    = (const float*)d_in[7];
    const float* Wproj  = (const float*)d_in[8];
    const float* bproj  = (const float*)d_in[9];
    const float* btab   = (const float*)d_in[10];
    const int*  relidx  = (const int*)d_in[11];
    const float* W1     = (const float*)d_in[12];
    const float* b1     = (const float*)d_in[13];
    const float* W2     = (const float*)d_in[14];
    const float* b2     = (const float*)d_in[15];
    bf16* ws = (bf16*)d_ws;              // weight images (~811 KB)

    k_prep<<<198, 256, 0, stream>>>(Wkv, Wproj, W1, W2, ws);
    k_fused<<<4096, 256, 0, stream>>>(skip, xup, g1, be1, ws, bkv,
                                      ws + 73728, bproj, btab, relidx,
                                      g2, be2, ws + 110592, b1, b2,
                                      (float*)d_out);
}